// Round 2
// baseline (221.075 us; speedup 1.0000x reference)
//
#include <hip/hip_runtime.h>
#include <cstdint>
#include <cstddef>

// SS2D: B=2, H=W=64 (L=4096), D_MODEL=96, D_INNER=192, K=4 dirs, N=16 states, DT_RANK=6.
// R2: scan: lane = channel, 16 states in-register, no shuffles.
// R3: k_gemm_xdbl -> bf16 MFMA 16x16x32; W_xp pre-packed fragment-order bf16.
// R4: exp2-folded A, readfirstlane(wid). R7: dt once in scanA -> dte; CHUNK 16.
// R8: compact dts_c stream; fast softplus; unroll 4; scanB 384x64.
// R9: k_gemm_in / k_gemm_out -> bf16 MFMA (were fp32 LDS-issue-bound, ~30us combined).
// R10: Pb replaced by scalar sdt + exp2 recompute in scanB; CHUNK 16->32.
// R11: dte eliminated (was 25MB write + 25MB read). scanC recomputes dt from the
//      compact dts_c stream (SGPR-uniform s_loads) + Wr[24]/bsum - bit-exact vs scanA.

#define CHUNK 32
#define NCK   128   // 4096 / CHUNK

#if __has_builtin(__builtin_amdgcn_exp2f)
#define EXP2(x) __builtin_amdgcn_exp2f(x)
#else
#define EXP2(x) exp2f(x)
#endif
#define LOG2E 1.44269504088896340736f
#define LN2   0.69314718055994530942f

typedef __attribute__((ext_vector_type(8))) short short8;
typedef __attribute__((ext_vector_type(8))) unsigned short ushort8;
typedef __attribute__((ext_vector_type(4))) float f32x4;

__device__ __forceinline__ float siluf(float x){ return x * (1.f/(1.f+__expf(-x))); }
__device__ __forceinline__ float softplus_fast(float v){
  float e  = EXP2(v*LOG2E);
  float sp = LN2*__log2f(1.f + e);
  return (v > 20.f) ? v : sp;
}
__device__ __forceinline__ unsigned short f2b(float f){
  uint32_t u = __float_as_uint(f);
  uint32_t r = (u + 0x7fffu + ((u>>16)&1u)) >> 16;
  return (unsigned short)r;
}
__device__ __forceinline__ short8 cast8(const float* p){
  float4 f0 = *(const float4*)p;
  float4 f1 = *(const float4*)(p+4);
  unsigned short t[8] = {f2b(f0.x),f2b(f0.y),f2b(f0.z),f2b(f0.w),
                         f2b(f1.x),f2b(f1.y),f2b(f1.z),f2b(f1.w)};
  return *(short8*)t;
}

// ---------------- Stage 0: pack W_xp + W_in + W_out into fragment-ordered bf16 ----------------
// seg0: W_xp 18432 entries [ph2][kc6][k32_4][pt6][lane]; seg1: W_in 4608 [k32_3][nt24][lane];
// seg2: W_out 2304 [k32_6][nt6][lane]. Entry = 8 bf16 (one lane's A/B fragment slice).
__global__ __launch_bounds__(256) void k_pack(
    const float* __restrict__ Wxp, const float* __restrict__ Win,
    const float* __restrict__ Wout,
    unsigned short* __restrict__ Wf, unsigned short* __restrict__ Wfin,
    unsigned short* __restrict__ Wfout)
{
  int tid = blockIdx.x*256 + threadIdx.x;   // 25344 lane-entries total
  int lane = tid & 63;
  int n = lane & 15, q = lane >> 4;
  if (tid < 18432){
    int rest = tid >> 6;
    int pt = rest % 6; rest /= 6;
    int k32 = rest & 3; rest >>= 2;
    int kc = rest % 6; int ph = rest / 6;
    int p = ph*96 + pt*16 + n;
    int kbase = kc*128 + k32*32 + q*8;
    unsigned short v[8];
#pragma unroll
    for (int j = 0; j < 8; j++)
      v[j] = (p < 152) ? f2b(Wxp[(size_t)p*768 + kbase + j]) : (unsigned short)0;
    *(ushort8*)(Wf + (size_t)tid*8) = *(ushort8*)v;
  } else if (tid < 23040){
    int e = tid - 18432;
    int rest = e >> 6;
    int nt = rest % 24, k32 = rest / 24;
    int p = nt*16 + n;
    int kbase = k32*32 + q*8;
    unsigned short v[8];
#pragma unroll
    for (int j = 0; j < 8; j++) v[j] = f2b(Win[(size_t)p*96 + kbase + j]);
    *(ushort8*)(Wfin + (size_t)e*8) = *(ushort8*)v;
  } else if (tid < 25344){
    int e = tid - 23040;
    int rest = e >> 6;
    int nt = rest % 6, k32 = rest / 6;
    int p = nt*16 + n;
    int kbase = k32*32 + q*8;
    unsigned short v[8];
#pragma unroll
    for (int j = 0; j < 8; j++) v[j] = f2b(Wout[(size_t)p*192 + kbase + j]);
    *(ushort8*)(Wfout + (size_t)e*8) = *(ushort8*)v;
  }
}

// ---------------- Stage 1 (MFMA): xz = x @ W_in^T + b_in; split -> xx, silu(z) ----------------
// grid 128 (M=64/block). 4 waves split N (96 each): 4 Mfrag x 6 Nfrag x 3 K32.
__global__ __launch_bounds__(256) void k_gemm_in(
    const float* __restrict__ x, const unsigned short* __restrict__ Wfin,
    const float* __restrict__ bias, float* __restrict__ xx, float* __restrict__ zs)
{
  const int tid = threadIdx.x;
  const int lane = tid & 63, w = tid >> 6;
  const int m0 = blockIdx.x*64;
  const int n = lane & 15, q = lane >> 4;
  f32x4 acc[4][6] = {};
#pragma unroll
  for (int k32 = 0; k32 < 3; k32++){
    int kb = k32*32 + q*8;
    short8 a[4];
#pragma unroll
    for (int mf = 0; mf < 4; mf++)
      a[mf] = cast8(x + (size_t)(m0 + mf*16 + n)*96 + kb);
#pragma unroll
    for (int j = 0; j < 6; j++){
      int nt = w*6 + j;
      short8 bfr = *(const short8*)(Wfin + ((size_t)(k32*24 + nt)*64 + lane)*8);
#pragma unroll
      for (int mf = 0; mf < 4; mf++)
        acc[mf][j] = __builtin_amdgcn_mfma_f32_16x16x32_bf16(a[mf], bfr, acc[mf][j], 0, 0, 0);
    }
  }
#pragma unroll
  for (int mf = 0; mf < 4; mf++)
#pragma unroll
    for (int j = 0; j < 6; j++){
      int nn = w*96 + j*16 + n;
      float bv = bias[nn];
#pragma unroll
      for (int reg = 0; reg < 4; reg++){
        int l = m0 + mf*16 + q*4 + reg;
        float v = acc[mf][j][reg] + bv;
        if (nn < 192) xx[(size_t)l*192 + nn] = v;
        else          zs[(size_t)l*192 + (nn-192)] = siluf(v);
      }
    }
}

// ---------------- Stage 2: depthwise 3x3 conv + silu; fp32 xc + bf16 xcb/xcTb ----------------
__global__ __launch_bounds__(256) void k_conv(
    const float* __restrict__ xx, const float* __restrict__ cw, const float* __restrict__ cb,
    float* __restrict__ xc,
    unsigned short* __restrict__ xcb, unsigned short* __restrict__ xcTb)
{
  int gid = blockIdx.x*256 + threadIdx.x;
  int c = gid % 192;
  int l = (gid/192) & 4095;
  int b = gid / (192*4096);
  int h = l >> 6, w = l & 63;
  float s = 0.f;
#pragma unroll
  for (int kh = 0; kh < 3; kh++){
    int h2 = h + kh - 1;
    if ((unsigned)h2 >= 64u) continue;
#pragma unroll
    for (int kw = 0; kw < 3; kw++){
      int w2 = w + kw - 1;
      if ((unsigned)w2 >= 64u) continue;
      s += xx[((size_t)b*4096 + h2*64 + w2)*192 + c] * cw[c*9 + kh*3 + kw];
    }
  }
  s = siluf(s + cb[c]);
  unsigned short sb = f2b(s);
  size_t i0 = ((size_t)b*4096 + l)*192 + c;
  xc[i0] = s; xcb[i0] = sb;
  int tl = (l & 63)*64 + (l >> 6);
  xcTb[((size_t)b*4096 + tl)*192 + c] = sb;
}

// ---------------- Stage 3 (MFMA): x_dbl = W_xp @ concat4(xc views) + b_xp ----------------
// Output packed x_dbl[b][k][l][48]: dts@0..5, B@8..23, C@24..39. Also compact dts_c[b][l][24].
__global__ __launch_bounds__(256) void k_gemm_xdbl(
    const unsigned short* __restrict__ xcb, const unsigned short* __restrict__ xcTb,
    const unsigned short* __restrict__ Wf, const float* __restrict__ bxp,
    float* __restrict__ xdbl, float* __restrict__ dts_c)
{
  __shared__ unsigned short Bsh[4*6*64*8];   // 24 KB
  const int tid = threadIdx.x;
  const int lane = tid & 63, w = tid >> 6;
  const int wl = w & 1, wp = w >> 1;
  const int l0 = blockIdx.x*64, ph = blockIdx.y, b = blockIdx.z;
  const int n = lane & 15, q = lane >> 4;
  f32x4 acc[2][3] = {};
  const unsigned short* slab0 = Wf + (size_t)ph*6*12288;
  for (int kc = 0; kc < 6; kc++){
    __syncthreads();
    const ushort8* srcp = (const ushort8*)(slab0 + (size_t)kc*12288);
#pragma unroll
    for (int t = 0; t < 6; t++) ((ushort8*)Bsh)[tid + t*256] = srcp[tid + t*256];
    __syncthreads();
#pragma unroll
    for (int k32 = 0; k32 < 4; k32++){
      int kk = kc*128 + k32*32;
      int dir = kk/192; int ch = kk%192 + q*8;
      const unsigned short* sp = (dir & 1) ? xcTb : xcb;
      bool rev = (dir >= 2);
      short8 a[2];
#pragma unroll
      for (int mt = 0; mt < 2; mt++){
        int ls = l0 + wl*32 + mt*16 + n;
        int row = rev ? 4095 - ls : ls;
        a[mt] = *(const short8*)(sp + ((size_t)b*4096 + row)*192 + ch);
      }
#pragma unroll
      for (int j = 0; j < 3; j++){
        short8 bfr = *(const short8*)&Bsh[((size_t)(k32*6 + wp*3 + j)*64 + lane)*8];
#pragma unroll
        for (int mt = 0; mt < 2; mt++)
          acc[mt][j] = __builtin_amdgcn_mfma_f32_16x16x32_bf16(a[mt], bfr, acc[mt][j], 0, 0, 0);
      }
    }
  }
#pragma unroll
  for (int mt = 0; mt < 2; mt++)
#pragma unroll
    for (int j = 0; j < 3; j++){
      int p = ph*96 + (wp*3+j)*16 + n;
      if (p < 152){
        int k = p/38, pp = p%38;
        int off = (pp < 6) ? pp : pp + 2;
        float bias = bxp[p];
#pragma unroll
        for (int reg = 0; reg < 4; reg++){
          int l = l0 + wl*32 + mt*16 + q*4 + reg;
          float val = acc[mt][j][reg] + bias;
          xdbl[(((size_t)b*4 + k)*4096 + l)*48 + off] = val;
          if (pp < 6) dts_c[((size_t)b*4096 + l)*24 + k*6 + pp] = val;
        }
      }
    }
}

// ---------------- Selective scan A: dt (24-term, single-stream dts_c) + chunk summary ----------------
// R11: no dte write; emits per-chunk scalar sdt + state summary Sb only.
__global__ __launch_bounds__(256) void k_scanA(
    const float* __restrict__ xc, const float* __restrict__ xdbl,
    const float* __restrict__ dts_c,
    const float* __restrict__ A_log, const float* __restrict__ Wdt,
    const float* __restrict__ bdt, const float* __restrict__ dtbias,
    float* __restrict__ sdtb, float* __restrict__ Sb)
{
  const int lane = threadIdx.x & 63;
  const int wid  = __builtin_amdgcn_readfirstlane(blockIdx.x*4 + (threadIdx.x >> 6));
  const int ck = wid & (NCK-1); const int g = wid / NCK;
  const int dblk = g % 3; const int bk = g / 3;
  const int k = bk & 3; const int b = bk >> 2;
  const int d = dblk*64 + lane; const int ch = k*192 + d;
  float An[16];  // -exp(A_log)*log2e
  {
    const float4* ap = (const float4*)(A_log + (size_t)ch*16);
#pragma unroll
    for (int i = 0; i < 4; i++){
      float4 t = ap[i];
      An[4*i+0] = -LOG2E*__expf(t.x); An[4*i+1] = -LOG2E*__expf(t.y);
      An[4*i+2] = -LOG2E*__expf(t.z); An[4*i+3] = -LOG2E*__expf(t.w);
    }
  }
  float Wr[24];
#pragma unroll
  for (int r = 0; r < 24; r++) Wr[r] = Wdt[(size_t)ch*24 + r];
  const float bsum = bdt[ch] + dtbias[ch];
  const int l0 = ck*CHUNK;
  const bool rev = (k >= 2);
  const int tr = k & 1;
  const int T0 = tr ? ((l0 & 63)*64 + (l0 >> 6)) : l0;
  const int rs = tr ? 64 : 1;
  const int row0 = rev ? 4095 - T0 : T0;
  const int rstep = (rev ? -rs : rs)*192;
  const float* up  = xc + ((size_t)b*4096 + row0)*192 + d;
  const float* qc  = dts_c + ((size_t)b*4096 + l0)*24;
  const float* xbc = xdbl + (((size_t)b*4 + k)*4096 + l0)*48;
  float h[16];
#pragma unroll
  for (int n = 0; n < 16; n++) h[n] = 0.f;
  float sdt = 0.f;
#pragma unroll 4
  for (int t = 0; t < CHUNK; t++){
    float u  = up[0];
    float4 B0 = *(const float4*)(xbc + 8);
    float4 B1 = *(const float4*)(xbc + 12);
    float4 B2 = *(const float4*)(xbc + 16);
    float4 B3 = *(const float4*)(xbc + 20);
    float Bv[16] = {B0.x,B0.y,B0.z,B0.w, B1.x,B1.y,B1.z,B1.w,
                    B2.x,B2.y,B2.z,B2.w, B3.x,B3.y,B3.z,B3.w};
    float4 q0 = *(const float4*)(qc);
    float4 q1 = *(const float4*)(qc + 4);
    float4 q2 = *(const float4*)(qc + 8);
    float4 q3 = *(const float4*)(qc + 12);
    float4 q4 = *(const float4*)(qc + 16);
    float4 q5 = *(const float4*)(qc + 20);
    float qv[24] = {q0.x,q0.y,q0.z,q0.w, q1.x,q1.y,q1.z,q1.w,
                    q2.x,q2.y,q2.z,q2.w, q3.x,q3.y,q3.z,q3.w,
                    q4.x,q4.y,q4.z,q4.w, q5.x,q5.y,q5.z,q5.w};
    float v0 = bsum, v1 = 0.f, v2 = 0.f, v3 = 0.f;
#pragma unroll
    for (int r = 0; r < 24; r += 4){
      v0 = fmaf(Wr[r+0], qv[r+0], v0);
      v1 = fmaf(Wr[r+1], qv[r+1], v1);
      v2 = fmaf(Wr[r+2], qv[r+2], v2);
      v3 = fmaf(Wr[r+3], qv[r+3], v3);
    }
    float dt = softplus_fast((v0+v1) + (v2+v3));
    float dtu = dt*u;
    sdt += dt;
#pragma unroll
    for (int n = 0; n < 16; n++){
      float dA = EXP2(dt*An[n]);
      h[n] = fmaf(dA, h[n], dtu*Bv[n]);
    }
    qc += 24; xbc += 48; up += rstep;
  }
  size_t base = ((size_t)wid*16)*64 + lane;
  sdtb[(size_t)wid*64 + lane] = sdt;
#pragma unroll
  for (int n = 0; n < 16; n++) Sb[base + n*64] = h[n];
}

// R10: chunk-decay recomputed from scalar sdt (bit-exact vs old Pb); serial chain = bare fmaf.
__global__ __launch_bounds__(64) void k_scanB(
    const float* __restrict__ A_log, const float* __restrict__ sdtb,
    const float* __restrict__ Sb, float* __restrict__ H0)
{
  int tid = blockIdx.x*64 + threadIdx.x;  // 24576 = 24 groups * 16 n * 64 lanes
  int lane = tid & 63; int n = (tid >> 6) & 15; int g = tid >> 10;
  int dblk = g % 3; int bk = g / 3; int k = bk & 3;
  int ch = k*192 + dblk*64 + lane;
  float An = -LOG2E*__expf(A_log[(size_t)ch*16 + n]);
  float h = 0.f;
#pragma unroll 8
  for (int ck = 0; ck < NCK; ck++){
    size_t sidx = ((size_t)(g*NCK + ck))*64 + lane;
    size_t idx  = (((size_t)(g*NCK + ck)*16) + n)*64 + lane;
    H0[idx] = h;
    h = fmaf(EXP2(An*sdtb[sidx]), h, Sb[idx]);
  }
}

// ---------------- Selective scan C: recomputes dt from dts_c (bit-exact vs scanA) ----------------
__global__ __launch_bounds__(256) void k_scanC(
    const float* __restrict__ xc, const float* __restrict__ xdbl,
    const float* __restrict__ dts_c,
    const float* __restrict__ A_log, const float* __restrict__ Wdt,
    const float* __restrict__ bdt, const float* __restrict__ dtbias,
    const float* __restrict__ Dskip,
    const float* __restrict__ H0, float* __restrict__ ys)
{
  const int lane = threadIdx.x & 63;
  const int wid  = __builtin_amdgcn_readfirstlane(blockIdx.x*4 + (threadIdx.x >> 6));
  const int ck = wid & (NCK-1); const int g = wid / NCK;
  const int dblk = g % 3; const int bk = g / 3;
  const int k = bk & 3; const int b = bk >> 2;
  const int d = dblk*64 + lane; const int ch = k*192 + d;
  float An[16];  // -exp(A_log)*log2e
  {
    const float4* ap = (const float4*)(A_log + (size_t)ch*16);
#pragma unroll
    for (int i = 0; i < 4; i++){
      float4 t = ap[i];
      An[4*i+0] = -LOG2E*__expf(t.x); An[4*i+1] = -LOG2E*__expf(t.y);
      An[4*i+2] = -LOG2E*__expf(t.z); An[4*i+3] = -LOG2E*__expf(t.w);
    }
  }
  float Wr[24];
#pragma unroll
  for (int r = 0; r < 24; r++) Wr[r] = Wdt[(size_t)ch*24 + r];
  const float bsum = bdt[ch] + dtbias[ch];
  const float Dv = Dskip[ch];
  const int l0 = ck*CHUNK;
  const bool rev = (k >= 2);
  const int tr = k & 1;
  const int T0 = tr ? ((l0 & 63)*64 + (l0 >> 6)) : l0;
  const int rs = tr ? 64 : 1;
  const int row0 = rev ? 4095 - T0 : T0;
  const int rstep = (rev ? -rs : rs)*192;
  const float* up  = xc + ((size_t)b*4096 + row0)*192 + d;
  const float* qc  = dts_c + ((size_t)b*4096 + l0)*24;
  const float* xbc = xdbl + (((size_t)b*4 + k)*4096 + l0)*48;
  float* ysp = ys + ((size_t)(k*2 + b))*4096*192 + (size_t)row0*192 + d;
  float h[16];
  size_t base = ((size_t)wid*16)*64 + lane;
#pragma unroll
  for (int n = 0; n < 16; n++) h[n] = H0[base + n*64];
#pragma unroll 4
  for (int t = 0; t < CHUNK; t++){
    float u  = up[0];
    float4 q0 = *(const float4*)(qc);
    float4 q1 = *(const float4*)(qc + 4);
    float4 q2 = *(const float4*)(qc + 8);
    float4 q3 = *(const float4*)(qc + 12);
    float4 q4 = *(const float4*)(qc + 16);
    float4 q5 = *(const float4*)(qc + 20);
    float qv[24] = {q0.x,q0.y,q0.z,q0.w, q1.x,q1.y,q1.z,q1.w,
                    q2.x,q2.y,q2.z,q2.w, q3.x,q3.y,q3.z,q3.w,
                    q4.x,q4.y,q4.z,q4.w, q5.x,q5.y,q5.z,q5.w};
    float v0 = bsum, v1 = 0.f, v2 = 0.f, v3 = 0.f;
#pragma unroll
    for (int r = 0; r < 24; r += 4){
      v0 = fmaf(Wr[r+0], qv[r+0], v0);
      v1 = fmaf(Wr[r+1], qv[r+1], v1);
      v2 = fmaf(Wr[r+2], qv[r+2], v2);
      v3 = fmaf(Wr[r+3], qv[r+3], v3);
    }
    float dt = softplus_fast((v0+v1) + (v2+v3));
    float4 B0 = *(const float4*)(xbc + 8);
    float4 B1 = *(const float4*)(xbc + 12);
    float4 B2 = *(const float4*)(xbc + 16);
    float4 B3 = *(const float4*)(xbc + 20);
    float4 C0 = *(const float4*)(xbc + 24);
    float4 C1 = *(const float4*)(xbc + 28);
    float4 C2 = *(const float4*)(xbc + 32);
    float4 C3 = *(const float4*)(xbc + 36);
    float Bv[16] = {B0.x,B0.y,B0.z,B0.w, B1.x,B1.y,B1.z,B1.w,
                    B2.x,B2.y,B2.z,B2.w, B3.x,B3.y,B3.z,B3.w};
    float Cv[16] = {C0.x,C0.y,C0.z,C0.w, C1.x,C1.y,C1.z,C1.w,
                    C2.x,C2.y,C2.z,C2.w, C3.x,C3.y,C3.z,C3.w};
    float dtu = dt*u;
    float y0 = u*Dv, y1 = 0.f;
#pragma unroll
    for (int n = 0; n < 16; n += 2){
      float dA0 = EXP2(dt*An[n]);
      float dA1 = EXP2(dt*An[n+1]);
      h[n]   = fmaf(dA0, h[n],   dtu*Bv[n]);
      h[n+1] = fmaf(dA1, h[n+1], dtu*Bv[n+1]);
      y0 = fmaf(h[n],   Cv[n],   y0);
      y1 = fmaf(h[n+1], Cv[n+1], y1);
    }
    ysp[0] = y0 + y1;
    qc += 24; xbc += 48; up += rstep; ysp += rstep;
  }
}

// ---------------- Stage 6: merge 4 planes + LayerNorm * silu(z) ----------------
__global__ __launch_bounds__(256) void k_ln(
    const float* __restrict__ ys, const float* __restrict__ zs,
    const float* __restrict__ gamma, const float* __restrict__ beta,
    float* __restrict__ yln)
{
  int row = blockIdx.x*4 + (threadIdx.x >> 6);
  int lane = threadIdx.x & 63;
  int b = row >> 12; int l = row & 4095;
  float v[3];
#pragma unroll
  for (int j = 0; j < 3; j++){
    int c = lane + j*64;
    float s = 0.f;
#pragma unroll
    for (int k = 0; k < 4; k++) s += ys[(((size_t)k*2 + b)*4096 + l)*192 + c];
    v[j] = s;
  }
  float tot = v[0] + v[1] + v[2];
#pragma unroll
  for (int o = 1; o < 64; o <<= 1) tot += __shfl_xor(tot, o);
  float mean = tot * (1.f/192.f);
  float d0 = v[0]-mean, d1 = v[1]-mean, d2 = v[2]-mean;
  float vs = d0*d0 + d1*d1 + d2*d2;
#pragma unroll
  for (int o = 1; o < 64; o <<= 1) vs += __shfl_xor(vs, o);
  float rstd = rsqrtf(vs*(1.f/192.f) + 1e-5f);
  float nd[3] = {d0, d1, d2};
#pragma unroll
  for (int j = 0; j < 3; j++){
    int c = lane + j*64;
    float val = nd[j]*rstd*gamma[c] + beta[c];
    val *= zs[(size_t)row*192 + c];
    yln[(size_t)row*192 + c] = val;
  }
}

// ---------------- Stage 7 (MFMA): out = y_ln @ W_out^T + b_out ----------------
// grid 128 (M=64/block). 4 waves split M (16 each): 1 Mfrag x 6 Nfrag x 6 K32.
__global__ __launch_bounds__(256) void k_gemm_out(
    const float* __restrict__ yln, const unsigned short* __restrict__ Wfout,
    const float* __restrict__ bout, float* __restrict__ out)
{
  const int tid = threadIdx.x;
  const int lane = tid & 63, w = tid >> 6;
  const int m0 = blockIdx.x*64 + w*16;
  const int n = lane & 15, q = lane >> 4;
  f32x4 acc[6] = {};
#pragma unroll
  for (int k32 = 0; k32 < 6; k32++){
    int kb = k32*32 + q*8;
    short8 a = cast8(yln + (size_t)(m0 + n)*192 + kb);
#pragma unroll
    for (int j = 0; j < 6; j++){
      short8 bfr = *(const short8*)(Wfout + ((size_t)(k32*6 + j)*64 + lane)*8);
      acc[j] = __builtin_amdgcn_mfma_f32_16x16x32_bf16(a, bfr, acc[j], 0, 0, 0);
    }
  }
#pragma unroll
  for (int j = 0; j < 6; j++){
    int nn = j*16 + n;
    float bv = bout[nn];
#pragma unroll
    for (int reg = 0; reg < 4; reg++){
      int m = m0 + q*4 + reg;
      out[(size_t)m*96 + nn] = acc[j][reg] + bv;
    }
  }
}

extern "C" void kernel_launch(void* const* d_in, const int* in_sizes, int n_in,
                              void* d_out, int out_size, void* d_ws, size_t ws_size,
                              hipStream_t stream)
{
  const float* x      = (const float*)d_in[0];
  const float* W_in   = (const float*)d_in[1];
  const float* b_in   = (const float*)d_in[2];
  const float* conv_w = (const float*)d_in[3];
  const float* conv_b = (const float*)d_in[4];
  const float* W_xp   = (const float*)d_in[5];
  const float* b_xp   = (const float*)d_in[6];
  const float* W_dt   = (const float*)d_in[7];
  const float* b_dt   = (const float*)d_in[8];
  const float* A_log  = (const float*)d_in[9];
  const float* D_skip = (const float*)d_in[10];
  const float* dt_bias= (const float*)d_in[11];
  const float* W_out  = (const float*)d_in[12];
  const float* b_out  = (const float*)d_in[13];
  const float* gamma  = (const float*)d_in[14];
  const float* beta   = (const float*)d_in[15];
  float* out = (float*)d_out;

  // Fully disjoint layout (floats). Total ~22.5M floats = 90 MB (< 256 MB ws).
  float* ws    = (float*)d_ws;
  float* xx    = ws;                 // 1572864
  float* zs    = ws + 1572864;       // 1572864
  float* xc    = ws + 3145728;       // 1572864
  float* xdbl  = ws + 4718592;       // 1572864
  float* ysb   = ws + 6291456;       // 6291456
  float* yln   = ws + 12582912;      // 1572864
  float* Sb    = ws + 14155776;      // 3145728
  float* H0    = ws + 17301504;      // 3145728
  float* sdtb  = ws + 20447232;      // 196608
  float* dts_c = ws + 20643840;      // 196608
  unsigned short* xcb   = (unsigned short*)(ws + 20840448); // 1572864 ushort
  unsigned short* xcTb  = xcb + 1572864;                    // 1572864 ushort
  unsigned short* Wf    = (unsigned short*)(ws + 22413312); // 147456 ushort
  unsigned short* Wfin  = (unsigned short*)(ws + 22487040); // 36864 ushort
  unsigned short* Wfout = (unsigned short*)(ws + 22505472); // 18432 ushort

  k_pack     <<<99,             256, 0, stream>>>(W_xp, W_in, W_out, Wf, Wfin, Wfout);
  k_gemm_in  <<<128,            256, 0, stream>>>(x, Wfin, b_in, xx, zs);
  k_conv     <<<6144,           256, 0, stream>>>(xx, conv_w, conv_b, xc, xcb, xcTb);
  k_gemm_xdbl<<<dim3(64, 2, 2), 256, 0, stream>>>(xcb, xcTb, Wf, b_xp, xdbl, dts_c);
  k_scanA    <<<768,            256, 0, stream>>>(xc, xdbl, dts_c, A_log, W_dt, b_dt, dt_bias, sdtb, Sb);
  k_scanB    <<<384,            64,  0, stream>>>(A_log, sdtb, Sb, H0);
  k_scanC    <<<768,            256, 0, stream>>>(xc, xdbl, dts_c, A_log, W_dt, b_dt, dt_bias, D_skip, H0, ysb);
  k_ln       <<<2048,           256, 0, stream>>>(ysb, zs, gamma, beta, yln);
  k_gemm_out <<<128,            256, 0, stream>>>(yln, Wfout, b_out, out);
}

// Round 3
// 209.470 us; speedup vs baseline: 1.0554x; 1.0554x over previous
//
#include <hip/hip_runtime.h>
#include <cstdint>
#include <cstddef>

// SS2D: B=2, H=W=64 (L=4096), D_MODEL=96, D_INNER=192, K=4 dirs, N=16 states, DT_RANK=6.
// R2: scan: lane = channel, 16 states in-register, no shuffles.
// R3: k_gemm_xdbl -> bf16 MFMA 16x16x32; W_xp pre-packed fragment-order bf16.
// R4: exp2-folded A, readfirstlane(wid). R7: dt once in scanA; CHUNK 16.
// R8: compact dts_c stream; fast softplus; unroll 4; scanB 384x64.
// R9: k_gemm_in / k_gemm_out -> bf16 MFMA.
// R10: Pb replaced by scalar sdt + exp2 recompute in scanB; CHUNK 16->32.
// R11: (REGRESSED +11us) dt recompute in scanC sat on the serial h-chain critical path.
// R12: scanC recurrence ELIMINATED. scanA emits {yloc = C.hloc + u*D, csdt} per step;
//      scanC computes y = C.(exp2(An*csdt) o H0) + yloc -- pure streaming, no dependency
//      chain, no xc/B reads. scanB unchanged (Sb = hloc(end), sdtb = csdt(end)).

#define CHUNK 32
#define NCK   128   // 4096 / CHUNK

#if __has_builtin(__builtin_amdgcn_exp2f)
#define EXP2(x) __builtin_amdgcn_exp2f(x)
#else
#define EXP2(x) exp2f(x)
#endif
#define LOG2E 1.44269504088896340736f
#define LN2   0.69314718055994530942f

typedef __attribute__((ext_vector_type(8))) short short8;
typedef __attribute__((ext_vector_type(8))) unsigned short ushort8;
typedef __attribute__((ext_vector_type(4))) float f32x4;

__device__ __forceinline__ float siluf(float x){ return x * (1.f/(1.f+__expf(-x))); }
__device__ __forceinline__ float softplus_fast(float v){
  float e  = EXP2(v*LOG2E);
  float sp = LN2*__log2f(1.f + e);
  return (v > 20.f) ? v : sp;
}
__device__ __forceinline__ unsigned short f2b(float f){
  uint32_t u = __float_as_uint(f);
  uint32_t r = (u + 0x7fffu + ((u>>16)&1u)) >> 16;
  return (unsigned short)r;
}
__device__ __forceinline__ short8 cast8(const float* p){
  float4 f0 = *(const float4*)p;
  float4 f1 = *(const float4*)(p+4);
  unsigned short t[8] = {f2b(f0.x),f2b(f0.y),f2b(f0.z),f2b(f0.w),
                         f2b(f1.x),f2b(f1.y),f2b(f1.z),f2b(f1.w)};
  return *(short8*)t;
}

// ---------------- Stage 0: pack W_xp + W_in + W_out into fragment-ordered bf16 ----------------
__global__ __launch_bounds__(256) void k_pack(
    const float* __restrict__ Wxp, const float* __restrict__ Win,
    const float* __restrict__ Wout,
    unsigned short* __restrict__ Wf, unsigned short* __restrict__ Wfin,
    unsigned short* __restrict__ Wfout)
{
  int tid = blockIdx.x*256 + threadIdx.x;   // 25344 lane-entries total
  int lane = tid & 63;
  int n = lane & 15, q = lane >> 4;
  if (tid < 18432){
    int rest = tid >> 6;
    int pt = rest % 6; rest /= 6;
    int k32 = rest & 3; rest >>= 2;
    int kc = rest % 6; int ph = rest / 6;
    int p = ph*96 + pt*16 + n;
    int kbase = kc*128 + k32*32 + q*8;
    unsigned short v[8];
#pragma unroll
    for (int j = 0; j < 8; j++)
      v[j] = (p < 152) ? f2b(Wxp[(size_t)p*768 + kbase + j]) : (unsigned short)0;
    *(ushort8*)(Wf + (size_t)tid*8) = *(ushort8*)v;
  } else if (tid < 23040){
    int e = tid - 18432;
    int rest = e >> 6;
    int nt = rest % 24, k32 = rest / 24;
    int p = nt*16 + n;
    int kbase = k32*32 + q*8;
    unsigned short v[8];
#pragma unroll
    for (int j = 0; j < 8; j++) v[j] = f2b(Win[(size_t)p*96 + kbase + j]);
    *(ushort8*)(Wfin + (size_t)e*8) = *(ushort8*)v;
  } else if (tid < 25344){
    int e = tid - 23040;
    int rest = e >> 6;
    int nt = rest % 6, k32 = rest / 6;
    int p = nt*16 + n;
    int kbase = k32*32 + q*8;
    unsigned short v[8];
#pragma unroll
    for (int j = 0; j < 8; j++) v[j] = f2b(Wout[(size_t)p*192 + kbase + j]);
    *(ushort8*)(Wfout + (size_t)e*8) = *(ushort8*)v;
  }
}

// ---------------- Stage 1 (MFMA): xz = x @ W_in^T + b_in; split -> xx, silu(z) ----------------
__global__ __launch_bounds__(256) void k_gemm_in(
    const float* __restrict__ x, const unsigned short* __restrict__ Wfin,
    const float* __restrict__ bias, float* __restrict__ xx, float* __restrict__ zs)
{
  const int tid = threadIdx.x;
  const int lane = tid & 63, w = tid >> 6;
  const int m0 = blockIdx.x*64;
  const int n = lane & 15, q = lane >> 4;
  f32x4 acc[4][6] = {};
#pragma unroll
  for (int k32 = 0; k32 < 3; k32++){
    int kb = k32*32 + q*8;
    short8 a[4];
#pragma unroll
    for (int mf = 0; mf < 4; mf++)
      a[mf] = cast8(x + (size_t)(m0 + mf*16 + n)*96 + kb);
#pragma unroll
    for (int j = 0; j < 6; j++){
      int nt = w*6 + j;
      short8 bfr = *(const short8*)(Wfin + ((size_t)(k32*24 + nt)*64 + lane)*8);
#pragma unroll
      for (int mf = 0; mf < 4; mf++)
        acc[mf][j] = __builtin_amdgcn_mfma_f32_16x16x32_bf16(a[mf], bfr, acc[mf][j], 0, 0, 0);
    }
  }
#pragma unroll
  for (int mf = 0; mf < 4; mf++)
#pragma unroll
    for (int j = 0; j < 6; j++){
      int nn = w*96 + j*16 + n;
      float bv = bias[nn];
#pragma unroll
      for (int reg = 0; reg < 4; reg++){
        int l = m0 + mf*16 + q*4 + reg;
        float v = acc[mf][j][reg] + bv;
        if (nn < 192) xx[(size_t)l*192 + nn] = v;
        else          zs[(size_t)l*192 + (nn-192)] = siluf(v);
      }
    }
}

// ---------------- Stage 2: depthwise 3x3 conv + silu; fp32 xc + bf16 xcb/xcTb ----------------
__global__ __launch_bounds__(256) void k_conv(
    const float* __restrict__ xx, const float* __restrict__ cw, const float* __restrict__ cb,
    float* __restrict__ xc,
    unsigned short* __restrict__ xcb, unsigned short* __restrict__ xcTb)
{
  int gid = blockIdx.x*256 + threadIdx.x;
  int c = gid % 192;
  int l = (gid/192) & 4095;
  int b = gid / (192*4096);
  int h = l >> 6, w = l & 63;
  float s = 0.f;
#pragma unroll
  for (int kh = 0; kh < 3; kh++){
    int h2 = h + kh - 1;
    if ((unsigned)h2 >= 64u) continue;
#pragma unroll
    for (int kw = 0; kw < 3; kw++){
      int w2 = w + kw - 1;
      if ((unsigned)w2 >= 64u) continue;
      s += xx[((size_t)b*4096 + h2*64 + w2)*192 + c] * cw[c*9 + kh*3 + kw];
    }
  }
  s = siluf(s + cb[c]);
  unsigned short sb = f2b(s);
  size_t i0 = ((size_t)b*4096 + l)*192 + c;
  xc[i0] = s; xcb[i0] = sb;
  int tl = (l & 63)*64 + (l >> 6);
  xcTb[((size_t)b*4096 + tl)*192 + c] = sb;
}

// ---------------- Stage 3 (MFMA): x_dbl = W_xp @ concat4(xc views) + b_xp ----------------
// Output packed x_dbl[b][k][l][48]: dts@0..5, B@8..23, C@24..39. Also compact dts_c[b][l][24].
__global__ __launch_bounds__(256) void k_gemm_xdbl(
    const unsigned short* __restrict__ xcb, const unsigned short* __restrict__ xcTb,
    const unsigned short* __restrict__ Wf, const float* __restrict__ bxp,
    float* __restrict__ xdbl, float* __restrict__ dts_c)
{
  __shared__ unsigned short Bsh[4*6*64*8];   // 24 KB
  const int tid = threadIdx.x;
  const int lane = tid & 63, w = tid >> 6;
  const int wl = w & 1, wp = w >> 1;
  const int l0 = blockIdx.x*64, ph = blockIdx.y, b = blockIdx.z;
  const int n = lane & 15, q = lane >> 4;
  f32x4 acc[2][3] = {};
  const unsigned short* slab0 = Wf + (size_t)ph*6*12288;
  for (int kc = 0; kc < 6; kc++){
    __syncthreads();
    const ushort8* srcp = (const ushort8*)(slab0 + (size_t)kc*12288);
#pragma unroll
    for (int t = 0; t < 6; t++) ((ushort8*)Bsh)[tid + t*256] = srcp[tid + t*256];
    __syncthreads();
#pragma unroll
    for (int k32 = 0; k32 < 4; k32++){
      int kk = kc*128 + k32*32;
      int dir = kk/192; int ch = kk%192 + q*8;
      const unsigned short* sp = (dir & 1) ? xcTb : xcb;
      bool rev = (dir >= 2);
      short8 a[2];
#pragma unroll
      for (int mt = 0; mt < 2; mt++){
        int ls = l0 + wl*32 + mt*16 + n;
        int row = rev ? 4095 - ls : ls;
        a[mt] = *(const short8*)(sp + ((size_t)b*4096 + row)*192 + ch);
      }
#pragma unroll
      for (int j = 0; j < 3; j++){
        short8 bfr = *(const short8*)&Bsh[((size_t)(k32*6 + wp*3 + j)*64 + lane)*8];
#pragma unroll
        for (int mt = 0; mt < 2; mt++)
          acc[mt][j] = __builtin_amdgcn_mfma_f32_16x16x32_bf16(a[mt], bfr, acc[mt][j], 0, 0, 0);
      }
    }
  }
#pragma unroll
  for (int mt = 0; mt < 2; mt++)
#pragma unroll
    for (int j = 0; j < 3; j++){
      int p = ph*96 + (wp*3+j)*16 + n;
      if (p < 152){
        int k = p/38, pp = p%38;
        int off = (pp < 6) ? pp : pp + 2;
        float bias = bxp[p];
#pragma unroll
        for (int reg = 0; reg < 4; reg++){
          int l = l0 + wl*32 + mt*16 + q*4 + reg;
          float val = acc[mt][j][reg] + bias;
          xdbl[(((size_t)b*4 + k)*4096 + l)*48 + off] = val;
          if (pp < 6) dts_c[((size_t)b*4096 + l)*24 + k*6 + pp] = val;
        }
      }
    }
}

// ---------------- Selective scan A: dt + local recurrence + {yloc,csdt} stream + chunk summary ----
// R12: per step also computes yloc = C.hloc + u*Dv and stores float2{yloc, csdt}.
__global__ __launch_bounds__(256) void k_scanA(
    const float* __restrict__ xc, const float* __restrict__ xdbl,
    const float* __restrict__ dts_c,
    const float* __restrict__ A_log, const float* __restrict__ Wdt,
    const float* __restrict__ bdt, const float* __restrict__ dtbias,
    const float* __restrict__ Dskip,
    float* __restrict__ ylcs, float* __restrict__ sdtb, float* __restrict__ Sb)
{
  const int lane = threadIdx.x & 63;
  const int wid  = __builtin_amdgcn_readfirstlane(blockIdx.x*4 + (threadIdx.x >> 6));
  const int ck = wid & (NCK-1); const int g = wid / NCK;
  const int dblk = g % 3; const int bk = g / 3;
  const int k = bk & 3; const int b = bk >> 2;
  const int d = dblk*64 + lane; const int ch = k*192 + d;
  float An[16];  // -exp(A_log)*log2e
  {
    const float4* ap = (const float4*)(A_log + (size_t)ch*16);
#pragma unroll
    for (int i = 0; i < 4; i++){
      float4 t = ap[i];
      An[4*i+0] = -LOG2E*__expf(t.x); An[4*i+1] = -LOG2E*__expf(t.y);
      An[4*i+2] = -LOG2E*__expf(t.z); An[4*i+3] = -LOG2E*__expf(t.w);
    }
  }
  float Wr[24];
#pragma unroll
  for (int r = 0; r < 24; r++) Wr[r] = Wdt[(size_t)ch*24 + r];
  const float bsum = bdt[ch] + dtbias[ch];
  const float Dv = Dskip[ch];
  const int l0 = ck*CHUNK;
  const bool rev = (k >= 2);
  const int tr = k & 1;
  const int T0 = tr ? ((l0 & 63)*64 + (l0 >> 6)) : l0;
  const int rs = tr ? 64 : 1;
  const int row0 = rev ? 4095 - T0 : T0;
  const int rstep = (rev ? -rs : rs)*192;
  const float* up  = xc + ((size_t)b*4096 + row0)*192 + d;
  const float* qc  = dts_c + ((size_t)b*4096 + l0)*24;
  const float* xbc = xdbl + (((size_t)b*4 + k)*4096 + l0)*48;
  float* ylp = ylcs + ((((size_t)b*4 + k)*4096 + l0)*192 + d)*2;
  float h[16];
#pragma unroll
  for (int n = 0; n < 16; n++) h[n] = 0.f;
  float sdt = 0.f;
#pragma unroll 4
  for (int t = 0; t < CHUNK; t++){
    float u  = up[0];
    float4 B0 = *(const float4*)(xbc + 8);
    float4 B1 = *(const float4*)(xbc + 12);
    float4 B2 = *(const float4*)(xbc + 16);
    float4 B3 = *(const float4*)(xbc + 20);
    float4 C0 = *(const float4*)(xbc + 24);
    float4 C1 = *(const float4*)(xbc + 28);
    float4 C2 = *(const float4*)(xbc + 32);
    float4 C3 = *(const float4*)(xbc + 36);
    float Bv[16] = {B0.x,B0.y,B0.z,B0.w, B1.x,B1.y,B1.z,B1.w,
                    B2.x,B2.y,B2.z,B2.w, B3.x,B3.y,B3.z,B3.w};
    float Cv[16] = {C0.x,C0.y,C0.z,C0.w, C1.x,C1.y,C1.z,C1.w,
                    C2.x,C2.y,C2.z,C2.w, C3.x,C3.y,C3.z,C3.w};
    float4 q0 = *(const float4*)(qc);
    float4 q1 = *(const float4*)(qc + 4);
    float4 q2 = *(const float4*)(qc + 8);
    float4 q3 = *(const float4*)(qc + 12);
    float4 q4 = *(const float4*)(qc + 16);
    float4 q5 = *(const float4*)(qc + 20);
    float qv[24] = {q0.x,q0.y,q0.z,q0.w, q1.x,q1.y,q1.z,q1.w,
                    q2.x,q2.y,q2.z,q2.w, q3.x,q3.y,q3.z,q3.w,
                    q4.x,q4.y,q4.z,q4.w, q5.x,q5.y,q5.z,q5.w};
    float v0 = bsum, v1 = 0.f, v2 = 0.f, v3 = 0.f;
#pragma unroll
    for (int r = 0; r < 24; r += 4){
      v0 = fmaf(Wr[r+0], qv[r+0], v0);
      v1 = fmaf(Wr[r+1], qv[r+1], v1);
      v2 = fmaf(Wr[r+2], qv[r+2], v2);
      v3 = fmaf(Wr[r+3], qv[r+3], v3);
    }
    float dt = softplus_fast((v0+v1) + (v2+v3));
    float dtu = dt*u;
    sdt += dt;
    float y0 = dtu ? 0.f : 0.f;  // placeholder folded below
    y0 = u*Dv;
    float y1 = 0.f;
#pragma unroll
    for (int n = 0; n < 16; n += 2){
      float dA0 = EXP2(dt*An[n]);
      float dA1 = EXP2(dt*An[n+1]);
      h[n]   = fmaf(dA0, h[n],   dtu*Bv[n]);
      h[n+1] = fmaf(dA1, h[n+1], dtu*Bv[n+1]);
      y0 = fmaf(h[n],   Cv[n],   y0);
      y1 = fmaf(h[n+1], Cv[n+1], y1);
    }
    *(float2*)ylp = make_float2(y0 + y1, sdt);
    qc += 24; xbc += 48; up += rstep; ylp += 384;
  }
  size_t base = ((size_t)wid*16)*64 + lane;
  sdtb[(size_t)wid*64 + lane] = sdt;
#pragma unroll
  for (int n = 0; n < 16; n++) Sb[base + n*64] = h[n];
}

// R10: chunk-decay recomputed from scalar sdt; serial chain = bare fmaf.
__global__ __launch_bounds__(64) void k_scanB(
    const float* __restrict__ A_log, const float* __restrict__ sdtb,
    const float* __restrict__ Sb, float* __restrict__ H0)
{
  int tid = blockIdx.x*64 + threadIdx.x;  // 24576 = 24 groups * 16 n * 64 lanes
  int lane = tid & 63; int n = (tid >> 6) & 15; int g = tid >> 10;
  int dblk = g % 3; int bk = g / 3; int k = bk & 3;
  int ch = k*192 + dblk*64 + lane;
  float An = -LOG2E*__expf(A_log[(size_t)ch*16 + n]);
  float h = 0.f;
#pragma unroll 8
  for (int ck = 0; ck < NCK; ck++){
    size_t sidx = ((size_t)(g*NCK + ck))*64 + lane;
    size_t idx  = (((size_t)(g*NCK + ck)*16) + n)*64 + lane;
    H0[idx] = h;
    h = fmaf(EXP2(An*sdtb[sidx]), h, Sb[idx]);
  }
}

// ---------------- Selective scan C (R12): NO recurrence. y = C.(exp2(An*csdt) o H0) + yloc ----
__global__ __launch_bounds__(256) void k_scanC(
    const float* __restrict__ xdbl, const float* __restrict__ A_log,
    const float* __restrict__ ylcs, const float* __restrict__ H0,
    float* __restrict__ ys)
{
  const int lane = threadIdx.x & 63;
  const int wid  = __builtin_amdgcn_readfirstlane(blockIdx.x*4 + (threadIdx.x >> 6));
  const int ck = wid & (NCK-1); const int g = wid / NCK;
  const int dblk = g % 3; const int bk = g / 3;
  const int k = bk & 3; const int b = bk >> 2;
  const int d = dblk*64 + lane; const int ch = k*192 + d;
  float An[16];  // -exp(A_log)*log2e
  {
    const float4* ap = (const float4*)(A_log + (size_t)ch*16);
#pragma unroll
    for (int i = 0; i < 4; i++){
      float4 t = ap[i];
      An[4*i+0] = -LOG2E*__expf(t.x); An[4*i+1] = -LOG2E*__expf(t.y);
      An[4*i+2] = -LOG2E*__expf(t.z); An[4*i+3] = -LOG2E*__expf(t.w);
    }
  }
  const int l0 = ck*CHUNK;
  const bool rev = (k >= 2);
  const int tr = k & 1;
  const int T0 = tr ? ((l0 & 63)*64 + (l0 >> 6)) : l0;
  const int rs = tr ? 64 : 1;
  const int row0 = rev ? 4095 - T0 : T0;
  const int rstep = (rev ? -rs : rs)*192;
  const float* xbc = xdbl + (((size_t)b*4 + k)*4096 + l0)*48;
  const float* ylp = ylcs + ((((size_t)b*4 + k)*4096 + l0)*192 + d)*2;
  float* ysp = ys + ((size_t)(k*2 + b))*4096*192 + (size_t)row0*192 + d;
  float h0r[16];
  size_t base = ((size_t)wid*16)*64 + lane;
#pragma unroll
  for (int n = 0; n < 16; n++) h0r[n] = H0[base + n*64];
#pragma unroll 4
  for (int t = 0; t < CHUNK; t++){
    float2 yc = *(const float2*)ylp;
    float4 C0 = *(const float4*)(xbc + 24);
    float4 C1 = *(const float4*)(xbc + 28);
    float4 C2 = *(const float4*)(xbc + 32);
    float4 C3 = *(const float4*)(xbc + 36);
    float Cv[16] = {C0.x,C0.y,C0.z,C0.w, C1.x,C1.y,C1.z,C1.w,
                    C2.x,C2.y,C2.z,C2.w, C3.x,C3.y,C3.z,C3.w};
    float cs = yc.y;
    float y0 = yc.x, y1 = 0.f;
#pragma unroll
    for (int n = 0; n < 16; n += 2){
      float e0 = EXP2(An[n]*cs)   * h0r[n];
      float e1 = EXP2(An[n+1]*cs) * h0r[n+1];
      y0 = fmaf(Cv[n],   e0, y0);
      y1 = fmaf(Cv[n+1], e1, y1);
    }
    ysp[0] = y0 + y1;
    ylp += 384; xbc += 48; ysp += rstep;
  }
}

// ---------------- Stage 6: merge 4 planes + LayerNorm * silu(z) ----------------
__global__ __launch_bounds__(256) void k_ln(
    const float* __restrict__ ys, const float* __restrict__ zs,
    const float* __restrict__ gamma, const float* __restrict__ beta,
    float* __restrict__ yln)
{
  int row = blockIdx.x*4 + (threadIdx.x >> 6);
  int lane = threadIdx.x & 63;
  int b = row >> 12; int l = row & 4095;
  float v[3];
#pragma unroll
  for (int j = 0; j < 3; j++){
    int c = lane + j*64;
    float s = 0.f;
#pragma unroll
    for (int k = 0; k < 4; k++) s += ys[(((size_t)k*2 + b)*4096 + l)*192 + c];
    v[j] = s;
  }
  float tot = v[0] + v[1] + v[2];
#pragma unroll
  for (int o = 1; o < 64; o <<= 1) tot += __shfl_xor(tot, o);
  float mean = tot * (1.f/192.f);
  float d0 = v[0]-mean, d1 = v[1]-mean, d2 = v[2]-mean;
  float vs = d0*d0 + d1*d1 + d2*d2;
#pragma unroll
  for (int o = 1; o < 64; o <<= 1) vs += __shfl_xor(vs, o);
  float rstd = rsqrtf(vs*(1.f/192.f) + 1e-5f);
  float nd[3] = {d0, d1, d2};
#pragma unroll
  for (int j = 0; j < 3; j++){
    int c = lane + j*64;
    float val = nd[j]*rstd*gamma[c] + beta[c];
    val *= zs[(size_t)row*192 + c];
    yln[(size_t)row*192 + c] = val;
  }
}

// ---------------- Stage 7 (MFMA): out = y_ln @ W_out^T + b_out ----------------
__global__ __launch_bounds__(256) void k_gemm_out(
    const float* __restrict__ yln, const unsigned short* __restrict__ Wfout,
    const float* __restrict__ bout, float* __restrict__ out)
{
  const int tid = threadIdx.x;
  const int lane = tid & 63, w = tid >> 6;
  const int m0 = blockIdx.x*64 + w*16;
  const int n = lane & 15, q = lane >> 4;
  f32x4 acc[6] = {};
#pragma unroll
  for (int k32 = 0; k32 < 6; k32++){
    int kb = k32*32 + q*8;
    short8 a = cast8(yln + (size_t)(m0 + n)*192 + kb);
#pragma unroll
    for (int j = 0; j < 6; j++){
      short8 bfr = *(const short8*)(Wfout + ((size_t)(k32*6 + j)*64 + lane)*8);
      acc[j] = __builtin_amdgcn_mfma_f32_16x16x32_bf16(a, bfr, acc[j], 0, 0, 0);
    }
  }
#pragma unroll
  for (int j = 0; j < 6; j++){
    int nn = j*16 + n;
    float bv = bout[nn];
#pragma unroll
    for (int reg = 0; reg < 4; reg++){
      int m = m0 + q*4 + reg;
      out[(size_t)m*96 + nn] = acc[j][reg] + bv;
    }
  }
}

extern "C" void kernel_launch(void* const* d_in, const int* in_sizes, int n_in,
                              void* d_out, int out_size, void* d_ws, size_t ws_size,
                              hipStream_t stream)
{
  const float* x      = (const float*)d_in[0];
  const float* W_in   = (const float*)d_in[1];
  const float* b_in   = (const float*)d_in[2];
  const float* conv_w = (const float*)d_in[3];
  const float* conv_b = (const float*)d_in[4];
  const float* W_xp   = (const float*)d_in[5];
  const float* b_xp   = (const float*)d_in[6];
  const float* W_dt   = (const float*)d_in[7];
  const float* b_dt   = (const float*)d_in[8];
  const float* A_log  = (const float*)d_in[9];
  const float* D_skip = (const float*)d_in[10];
  const float* dt_bias= (const float*)d_in[11];
  const float* W_out  = (const float*)d_in[12];
  const float* b_out  = (const float*)d_in[13];
  const float* gamma  = (const float*)d_in[14];
  const float* beta   = (const float*)d_in[15];
  float* out = (float*)d_out;

  // Fully disjoint layout (floats). Total ~35.1M floats = 140 MB (< 256 MB ws).
  float* ws    = (float*)d_ws;
  float* xx    = ws;                 // 1572864
  float* zs    = ws + 1572864;       // 1572864
  float* xc    = ws + 3145728;       // 1572864
  float* xdbl  = ws + 4718592;       // 1572864
  float* ysb   = ws + 6291456;       // 6291456
  float* yln   = ws + 12582912;      // 1572864
  float* Sb    = ws + 14155776;      // 3145728
  float* H0    = ws + 17301504;      // 3145728
  float* sdtb  = ws + 20447232;      // 196608
  float* dts_c = ws + 20643840;      // 196608
  float* ylcs  = ws + 20840448;      // 12582912 (float2 stream {yloc,csdt})
  unsigned short* xcb   = (unsigned short*)(ws + 33423360); // 1572864 ushort
  unsigned short* xcTb  = xcb + 1572864;                    // 1572864 ushort
  unsigned short* Wf    = (unsigned short*)(ws + 34996224); // 147456 ushort
  unsigned short* Wfin  = (unsigned short*)(ws + 35069952); // 36864 ushort
  unsigned short* Wfout = (unsigned short*)(ws + 35088384); // 18432 ushort

  k_pack     <<<99,             256, 0, stream>>>(W_xp, W_in, W_out, Wf, Wfin, Wfout);
  k_gemm_in  <<<128,            256, 0, stream>>>(x, Wfin, b_in, xx, zs);
  k_conv     <<<6144,           256, 0, stream>>>(xx, conv_w, conv_b, xc, xcb, xcTb);
  k_gemm_xdbl<<<dim3(64, 2, 2), 256, 0, stream>>>(xcb, xcTb, Wf, b_xp, xdbl, dts_c);
  k_scanA    <<<768,            256, 0, stream>>>(xc, xdbl, dts_c, A_log, W_dt, b_dt, dt_bias, D_skip, ylcs, sdtb, Sb);
  k_scanB    <<<384,            64,  0, stream>>>(A_log, sdtb, Sb, H0);
  k_scanC    <<<768,            256, 0, stream>>>(xdbl, A_log, ylcs, H0, ysb);
  k_ln       <<<2048,           256, 0, stream>>>(ysb, zs, gamma, beta, yln);
  k_gemm_out <<<128,            256, 0, stream>>>(yln, Wfout, b_out, out);
}

// Round 4
// 207.268 us; speedup vs baseline: 1.0666x; 1.0106x over previous
//
#include <hip/hip_runtime.h>
#include <cstdint>
#include <cstddef>

// SS2D: B=2, H=W=64 (L=4096), D_MODEL=96, D_INNER=192, K=4 dirs, N=16 states, DT_RANK=6.
// R2: scan: lane = channel, 16 states in-register, no shuffles.
// R3: k_gemm_xdbl -> bf16 MFMA 16x16x32; W_xp pre-packed fragment-order bf16.
// R9: k_gemm_in / k_gemm_out -> bf16 MFMA.
// R10: Pb -> scalar sdt + exp2 recompute in scanB.
// R11: (REGRESSED) dt recompute in scanC sat on serial h-chain.
// R12: scanC recurrence eliminated via {yloc,csdt} stream. 209.5us == R10's 210 despite
//      +50MB traffic -> scans are LATENCY-bound, not BW-bound.
// R13: occupancy push. CHUNK 16 (scanA 3->4 waves/SIMD, scanC 5-6); k_ln+k_gemm_out fused
//      (kills yln HBM round-trip + a launch, 256 blocks = full CU coverage);
//      k_gemm_in 32-row tiles (grid 256, all CUs busy).

#define CHUNK 16
#define NCK   256   // 4096 / CHUNK

#if __has_builtin(__builtin_amdgcn_exp2f)
#define EXP2(x) __builtin_amdgcn_exp2f(x)
#else
#define EXP2(x) exp2f(x)
#endif
#define LOG2E 1.44269504088896340736f
#define LN2   0.69314718055994530942f

typedef __attribute__((ext_vector_type(8))) short short8;
typedef __attribute__((ext_vector_type(8))) unsigned short ushort8;
typedef __attribute__((ext_vector_type(4))) float f32x4;

__device__ __forceinline__ float siluf(float x){ return x * (1.f/(1.f+__expf(-x))); }
__device__ __forceinline__ float softplus_fast(float v){
  float e  = EXP2(v*LOG2E);
  float sp = LN2*__log2f(1.f + e);
  return (v > 20.f) ? v : sp;
}
__device__ __forceinline__ unsigned short f2b(float f){
  uint32_t u = __float_as_uint(f);
  uint32_t r = (u + 0x7fffu + ((u>>16)&1u)) >> 16;
  return (unsigned short)r;
}
__device__ __forceinline__ short8 cast8(const float* p){
  float4 f0 = *(const float4*)p;
  float4 f1 = *(const float4*)(p+4);
  unsigned short t[8] = {f2b(f0.x),f2b(f0.y),f2b(f0.z),f2b(f0.w),
                         f2b(f1.x),f2b(f1.y),f2b(f1.z),f2b(f1.w)};
  return *(short8*)t;
}

// ---------------- Stage 0: pack W_xp + W_in + W_out into fragment-ordered bf16 ----------------
__global__ __launch_bounds__(256) void k_pack(
    const float* __restrict__ Wxp, const float* __restrict__ Win,
    const float* __restrict__ Wout,
    unsigned short* __restrict__ Wf, unsigned short* __restrict__ Wfin,
    unsigned short* __restrict__ Wfout)
{
  int tid = blockIdx.x*256 + threadIdx.x;   // 25344 lane-entries total
  int lane = tid & 63;
  int n = lane & 15, q = lane >> 4;
  if (tid < 18432){
    int rest = tid >> 6;
    int pt = rest % 6; rest /= 6;
    int k32 = rest & 3; rest >>= 2;
    int kc = rest % 6; int ph = rest / 6;
    int p = ph*96 + pt*16 + n;
    int kbase = kc*128 + k32*32 + q*8;
    unsigned short v[8];
#pragma unroll
    for (int j = 0; j < 8; j++)
      v[j] = (p < 152) ? f2b(Wxp[(size_t)p*768 + kbase + j]) : (unsigned short)0;
    *(ushort8*)(Wf + (size_t)tid*8) = *(ushort8*)v;
  } else if (tid < 23040){
    int e = tid - 18432;
    int rest = e >> 6;
    int nt = rest % 24, k32 = rest / 24;
    int p = nt*16 + n;
    int kbase = k32*32 + q*8;
    unsigned short v[8];
#pragma unroll
    for (int j = 0; j < 8; j++) v[j] = f2b(Win[(size_t)p*96 + kbase + j]);
    *(ushort8*)(Wfin + (size_t)e*8) = *(ushort8*)v;
  } else if (tid < 25344){
    int e = tid - 23040;
    int rest = e >> 6;
    int nt = rest % 6, k32 = rest / 6;
    int p = nt*16 + n;
    int kbase = k32*32 + q*8;
    unsigned short v[8];
#pragma unroll
    for (int j = 0; j < 8; j++) v[j] = f2b(Wout[(size_t)p*192 + kbase + j]);
    *(ushort8*)(Wfout + (size_t)e*8) = *(ushort8*)v;
  }
}

// ---------------- Stage 1 (MFMA): xz = x @ W_in^T + b_in; split -> xx, silu(z) ----------------
// R13: 32-row tiles, grid 256 (full CU coverage). 4 waves split N: 2 Mfrag x 6 Nfrag x 3 K32.
__global__ __launch_bounds__(256) void k_gemm_in(
    const float* __restrict__ x, const unsigned short* __restrict__ Wfin,
    const float* __restrict__ bias, float* __restrict__ xx, float* __restrict__ zs)
{
  const int tid = threadIdx.x;
  const int lane = tid & 63, w = tid >> 6;
  const int m0 = blockIdx.x*32;
  const int n = lane & 15, q = lane >> 4;
  f32x4 acc[2][6] = {};
#pragma unroll
  for (int k32 = 0; k32 < 3; k32++){
    int kb = k32*32 + q*8;
    short8 a[2];
#pragma unroll
    for (int mf = 0; mf < 2; mf++)
      a[mf] = cast8(x + (size_t)(m0 + mf*16 + n)*96 + kb);
#pragma unroll
    for (int j = 0; j < 6; j++){
      int nt = w*6 + j;
      short8 bfr = *(const short8*)(Wfin + ((size_t)(k32*24 + nt)*64 + lane)*8);
#pragma unroll
      for (int mf = 0; mf < 2; mf++)
        acc[mf][j] = __builtin_amdgcn_mfma_f32_16x16x32_bf16(a[mf], bfr, acc[mf][j], 0, 0, 0);
    }
  }
#pragma unroll
  for (int mf = 0; mf < 2; mf++)
#pragma unroll
    for (int j = 0; j < 6; j++){
      int nn = w*96 + j*16 + n;
      float bv = bias[nn];
#pragma unroll
      for (int reg = 0; reg < 4; reg++){
        int l = m0 + mf*16 + q*4 + reg;
        float v = acc[mf][j][reg] + bv;
        if (nn < 192) xx[(size_t)l*192 + nn] = v;
        else          zs[(size_t)l*192 + (nn-192)] = siluf(v);
      }
    }
}

// ---------------- Stage 2: depthwise 3x3 conv + silu; fp32 xc + bf16 xcb/xcTb ----------------
__global__ __launch_bounds__(256) void k_conv(
    const float* __restrict__ xx, const float* __restrict__ cw, const float* __restrict__ cb,
    float* __restrict__ xc,
    unsigned short* __restrict__ xcb, unsigned short* __restrict__ xcTb)
{
  int gid = blockIdx.x*256 + threadIdx.x;
  int c = gid % 192;
  int l = (gid/192) & 4095;
  int b = gid / (192*4096);
  int h = l >> 6, w = l & 63;
  float s = 0.f;
#pragma unroll
  for (int kh = 0; kh < 3; kh++){
    int h2 = h + kh - 1;
    if ((unsigned)h2 >= 64u) continue;
#pragma unroll
    for (int kw = 0; kw < 3; kw++){
      int w2 = w + kw - 1;
      if ((unsigned)w2 >= 64u) continue;
      s += xx[((size_t)b*4096 + h2*64 + w2)*192 + c] * cw[c*9 + kh*3 + kw];
    }
  }
  s = siluf(s + cb[c]);
  unsigned short sb = f2b(s);
  size_t i0 = ((size_t)b*4096 + l)*192 + c;
  xc[i0] = s; xcb[i0] = sb;
  int tl = (l & 63)*64 + (l >> 6);
  xcTb[((size_t)b*4096 + tl)*192 + c] = sb;
}

// ---------------- Stage 3 (MFMA): x_dbl = W_xp @ concat4(xc views) + b_xp ----------------
// Output packed x_dbl[b][k][l][48]: dts@0..5, B@8..23, C@24..39. Also compact dts_c[b][l][24].
__global__ __launch_bounds__(256) void k_gemm_xdbl(
    const unsigned short* __restrict__ xcb, const unsigned short* __restrict__ xcTb,
    const unsigned short* __restrict__ Wf, const float* __restrict__ bxp,
    float* __restrict__ xdbl, float* __restrict__ dts_c)
{
  __shared__ unsigned short Bsh[4*6*64*8];   // 24 KB
  const int tid = threadIdx.x;
  const int lane = tid & 63, w = tid >> 6;
  const int wl = w & 1, wp = w >> 1;
  const int l0 = blockIdx.x*64, ph = blockIdx.y, b = blockIdx.z;
  const int n = lane & 15, q = lane >> 4;
  f32x4 acc[2][3] = {};
  const unsigned short* slab0 = Wf + (size_t)ph*6*12288;
  for (int kc = 0; kc < 6; kc++){
    __syncthreads();
    const ushort8* srcp = (const ushort8*)(slab0 + (size_t)kc*12288);
#pragma unroll
    for (int t = 0; t < 6; t++) ((ushort8*)Bsh)[tid + t*256] = srcp[tid + t*256];
    __syncthreads();
#pragma unroll
    for (int k32 = 0; k32 < 4; k32++){
      int kk = kc*128 + k32*32;
      int dir = kk/192; int ch = kk%192 + q*8;
      const unsigned short* sp = (dir & 1) ? xcTb : xcb;
      bool rev = (dir >= 2);
      short8 a[2];
#pragma unroll
      for (int mt = 0; mt < 2; mt++){
        int ls = l0 + wl*32 + mt*16 + n;
        int row = rev ? 4095 - ls : ls;
        a[mt] = *(const short8*)(sp + ((size_t)b*4096 + row)*192 + ch);
      }
#pragma unroll
      for (int j = 0; j < 3; j++){
        short8 bfr = *(const short8*)&Bsh[((size_t)(k32*6 + wp*3 + j)*64 + lane)*8];
#pragma unroll
        for (int mt = 0; mt < 2; mt++)
          acc[mt][j] = __builtin_amdgcn_mfma_f32_16x16x32_bf16(a[mt], bfr, acc[mt][j], 0, 0, 0);
      }
    }
  }
#pragma unroll
  for (int mt = 0; mt < 2; mt++)
#pragma unroll
    for (int j = 0; j < 3; j++){
      int p = ph*96 + (wp*3+j)*16 + n;
      if (p < 152){
        int k = p/38, pp = p%38;
        int off = (pp < 6) ? pp : pp + 2;
        float bias = bxp[p];
#pragma unroll
        for (int reg = 0; reg < 4; reg++){
          int l = l0 + wl*32 + mt*16 + q*4 + reg;
          float val = acc[mt][j][reg] + bias;
          xdbl[(((size_t)b*4 + k)*4096 + l)*48 + off] = val;
          if (pp < 6) dts_c[((size_t)b*4096 + l)*24 + k*6 + pp] = val;
        }
      }
    }
}

// ---------------- Selective scan A: dt + local recurrence + {yloc,csdt} stream + chunk summary ----
__global__ __launch_bounds__(256) void k_scanA(
    const float* __restrict__ xc, const float* __restrict__ xdbl,
    const float* __restrict__ dts_c,
    const float* __restrict__ A_log, const float* __restrict__ Wdt,
    const float* __restrict__ bdt, const float* __restrict__ dtbias,
    const float* __restrict__ Dskip,
    float* __restrict__ ylcs, float* __restrict__ sdtb, float* __restrict__ Sb)
{
  const int lane = threadIdx.x & 63;
  const int wid  = __builtin_amdgcn_readfirstlane(blockIdx.x*4 + (threadIdx.x >> 6));
  const int ck = wid & (NCK-1); const int g = wid / NCK;
  const int dblk = g % 3; const int bk = g / 3;
  const int k = bk & 3; const int b = bk >> 2;
  const int d = dblk*64 + lane; const int ch = k*192 + d;
  float An[16];  // -exp(A_log)*log2e
  {
    const float4* ap = (const float4*)(A_log + (size_t)ch*16);
#pragma unroll
    for (int i = 0; i < 4; i++){
      float4 t = ap[i];
      An[4*i+0] = -LOG2E*__expf(t.x); An[4*i+1] = -LOG2E*__expf(t.y);
      An[4*i+2] = -LOG2E*__expf(t.z); An[4*i+3] = -LOG2E*__expf(t.w);
    }
  }
  float Wr[24];
#pragma unroll
  for (int r = 0; r < 24; r++) Wr[r] = Wdt[(size_t)ch*24 + r];
  const float bsum = bdt[ch] + dtbias[ch];
  const float Dv = Dskip[ch];
  const int l0 = ck*CHUNK;
  const bool rev = (k >= 2);
  const int tr = k & 1;
  const int T0 = tr ? ((l0 & 63)*64 + (l0 >> 6)) : l0;
  const int rs = tr ? 64 : 1;
  const int row0 = rev ? 4095 - T0 : T0;
  const int rstep = (rev ? -rs : rs)*192;
  const float* up  = xc + ((size_t)b*4096 + row0)*192 + d;
  const float* qc  = dts_c + ((size_t)b*4096 + l0)*24;
  const float* xbc = xdbl + (((size_t)b*4 + k)*4096 + l0)*48;
  float* ylp = ylcs + ((((size_t)b*4 + k)*4096 + l0)*192 + d)*2;
  float h[16];
#pragma unroll
  for (int n = 0; n < 16; n++) h[n] = 0.f;
  float sdt = 0.f;
#pragma unroll 4
  for (int t = 0; t < CHUNK; t++){
    float u  = up[0];
    float4 B0 = *(const float4*)(xbc + 8);
    float4 B1 = *(const float4*)(xbc + 12);
    float4 B2 = *(const float4*)(xbc + 16);
    float4 B3 = *(const float4*)(xbc + 20);
    float4 C0 = *(const float4*)(xbc + 24);
    float4 C1 = *(const float4*)(xbc + 28);
    float4 C2 = *(const float4*)(xbc + 32);
    float4 C3 = *(const float4*)(xbc + 36);
    float Bv[16] = {B0.x,B0.y,B0.z,B0.w, B1.x,B1.y,B1.z,B1.w,
                    B2.x,B2.y,B2.z,B2.w, B3.x,B3.y,B3.z,B3.w};
    float Cv[16] = {C0.x,C0.y,C0.z,C0.w, C1.x,C1.y,C1.z,C1.w,
                    C2.x,C2.y,C2.z,C2.w, C3.x,C3.y,C3.z,C3.w};
    float4 q0 = *(const float4*)(qc);
    float4 q1 = *(const float4*)(qc + 4);
    float4 q2 = *(const float4*)(qc + 8);
    float4 q3 = *(const float4*)(qc + 12);
    float4 q4 = *(const float4*)(qc + 16);
    float4 q5 = *(const float4*)(qc + 20);
    float qv[24] = {q0.x,q0.y,q0.z,q0.w, q1.x,q1.y,q1.z,q1.w,
                    q2.x,q2.y,q2.z,q2.w, q3.x,q3.y,q3.z,q3.w,
                    q4.x,q4.y,q4.z,q4.w, q5.x,q5.y,q5.z,q5.w};
    float v0 = bsum, v1 = 0.f, v2 = 0.f, v3 = 0.f;
#pragma unroll
    for (int r = 0; r < 24; r += 4){
      v0 = fmaf(Wr[r+0], qv[r+0], v0);
      v1 = fmaf(Wr[r+1], qv[r+1], v1);
      v2 = fmaf(Wr[r+2], qv[r+2], v2);
      v3 = fmaf(Wr[r+3], qv[r+3], v3);
    }
    float dt = softplus_fast((v0+v1) + (v2+v3));
    float dtu = dt*u;
    sdt += dt;
    float y0 = u*Dv;
    float y1 = 0.f;
#pragma unroll
    for (int n = 0; n < 16; n += 2){
      float dA0 = EXP2(dt*An[n]);
      float dA1 = EXP2(dt*An[n+1]);
      h[n]   = fmaf(dA0, h[n],   dtu*Bv[n]);
      h[n+1] = fmaf(dA1, h[n+1], dtu*Bv[n+1]);
      y0 = fmaf(h[n],   Cv[n],   y0);
      y1 = fmaf(h[n+1], Cv[n+1], y1);
    }
    *(float2*)ylp = make_float2(y0 + y1, sdt);
    qc += 24; xbc += 48; up += rstep; ylp += 384;
  }
  size_t base = ((size_t)wid*16)*64 + lane;
  sdtb[(size_t)wid*64 + lane] = sdt;
#pragma unroll
  for (int n = 0; n < 16; n++) Sb[base + n*64] = h[n];
}

// Chunk-decay recomputed from scalar sdt; serial chain = bare fmaf.
__global__ __launch_bounds__(64) void k_scanB(
    const float* __restrict__ A_log, const float* __restrict__ sdtb,
    const float* __restrict__ Sb, float* __restrict__ H0)
{
  int tid = blockIdx.x*64 + threadIdx.x;  // 24576 = 24 groups * 16 n * 64 lanes
  int lane = tid & 63; int n = (tid >> 6) & 15; int g = tid >> 10;
  int dblk = g % 3; int bk = g / 3; int k = bk & 3;
  int ch = k*192 + dblk*64 + lane;
  float An = -LOG2E*__expf(A_log[(size_t)ch*16 + n]);
  float h = 0.f;
#pragma unroll 8
  for (int ck = 0; ck < NCK; ck++){
    size_t sidx = ((size_t)(g*NCK + ck))*64 + lane;
    size_t idx  = (((size_t)(g*NCK + ck)*16) + n)*64 + lane;
    H0[idx] = h;
    h = fmaf(EXP2(An*sdtb[sidx]), h, Sb[idx]);
  }
}

// ---------------- Selective scan C: NO recurrence. y = C.(exp2(An*csdt) o H0) + yloc ----------
__global__ __launch_bounds__(256) void k_scanC(
    const float* __restrict__ xdbl, const float* __restrict__ A_log,
    const float* __restrict__ ylcs, const float* __restrict__ H0,
    float* __restrict__ ys)
{
  const int lane = threadIdx.x & 63;
  const int wid  = __builtin_amdgcn_readfirstlane(blockIdx.x*4 + (threadIdx.x >> 6));
  const int ck = wid & (NCK-1); const int g = wid / NCK;
  const int dblk = g % 3; const int bk = g / 3;
  const int k = bk & 3; const int b = bk >> 2;
  const int d = dblk*64 + lane; const int ch = k*192 + d;
  float An[16];  // -exp(A_log)*log2e
  {
    const float4* ap = (const float4*)(A_log + (size_t)ch*16);
#pragma unroll
    for (int i = 0; i < 4; i++){
      float4 t = ap[i];
      An[4*i+0] = -LOG2E*__expf(t.x); An[4*i+1] = -LOG2E*__expf(t.y);
      An[4*i+2] = -LOG2E*__expf(t.z); An[4*i+3] = -LOG2E*__expf(t.w);
    }
  }
  const int l0 = ck*CHUNK;
  const bool rev = (k >= 2);
  const int tr = k & 1;
  const int T0 = tr ? ((l0 & 63)*64 + (l0 >> 6)) : l0;
  const int rs = tr ? 64 : 1;
  const int row0 = rev ? 4095 - T0 : T0;
  const int rstep = (rev ? -rs : rs)*192;
  const float* xbc = xdbl + (((size_t)b*4 + k)*4096 + l0)*48;
  const float* ylp = ylcs + ((((size_t)b*4 + k)*4096 + l0)*192 + d)*2;
  float* ysp = ys + ((size_t)(k*2 + b))*4096*192 + (size_t)row0*192 + d;
  float h0r[16];
  size_t base = ((size_t)wid*16)*64 + lane;
#pragma unroll
  for (int n = 0; n < 16; n++) h0r[n] = H0[base + n*64];
#pragma unroll 4
  for (int t = 0; t < CHUNK; t++){
    float2 yc = *(const float2*)ylp;
    float4 C0 = *(const float4*)(xbc + 24);
    float4 C1 = *(const float4*)(xbc + 28);
    float4 C2 = *(const float4*)(xbc + 32);
    float4 C3 = *(const float4*)(xbc + 36);
    float Cv[16] = {C0.x,C0.y,C0.z,C0.w, C1.x,C1.y,C1.z,C1.w,
                    C2.x,C2.y,C2.z,C2.w, C3.x,C3.y,C3.z,C3.w};
    float cs = yc.y;
    float y0 = yc.x, y1 = 0.f;
#pragma unroll
    for (int n = 0; n < 16; n += 2){
      float e0 = EXP2(An[n]*cs)   * h0r[n];
      float e1 = EXP2(An[n+1]*cs) * h0r[n+1];
      y0 = fmaf(Cv[n],   e0, y0);
      y1 = fmaf(Cv[n+1], e1, y1);
    }
    ysp[0] = y0 + y1;
    ylp += 384; xbc += 48; ysp += rstep;
  }
}

// ---------------- Stage 6+7 fused (R13): merge + LayerNorm*silu(z) -> LDS bf16 -> MFMA out ----
// 32 rows/block, grid 256. Phase 1: thread = (row 0..31, octant 0..7) -> 24 channels;
// LN reduce via 8-lane shfl_xor. Phase 2: 4 waves = 2 Mfrag x 2 Nhalf, 6 K32.
__global__ __launch_bounds__(256) void k_lngemm(
    const float* __restrict__ ys, const float* __restrict__ zs,
    const float* __restrict__ gamma, const float* __restrict__ beta,
    const unsigned short* __restrict__ Wfout, const float* __restrict__ bout,
    float* __restrict__ out)
{
  __shared__ unsigned short Ash[32*200];   // 12.5 KB, stride 200 ushorts
  const int tid = threadIdx.x;
  {
    const int row_l = tid >> 3, o = tid & 7;
    const int row = blockIdx.x*32 + row_l;
    const int b = row >> 12, l = row & 4095;
    const int c0 = o*24;
    float s[24];
#pragma unroll
    for (int j = 0; j < 6; j++){
      float sx = 0.f, sy = 0.f, sz = 0.f, sw = 0.f;
#pragma unroll
      for (int k = 0; k < 4; k++){
        float4 t = *(const float4*)(ys + (((size_t)(k*2+b))*4096 + l)*192 + c0 + j*4);
        sx += t.x; sy += t.y; sz += t.z; sw += t.w;
      }
      s[j*4+0]=sx; s[j*4+1]=sy; s[j*4+2]=sz; s[j*4+3]=sw;
    }
    float tot = 0.f;
#pragma unroll
    for (int j = 0; j < 24; j++) tot += s[j];
#pragma unroll
    for (int off = 1; off < 8; off <<= 1) tot += __shfl_xor(tot, off);
    float mean = tot*(1.f/192.f);
    float vs = 0.f;
#pragma unroll
    for (int j = 0; j < 24; j++){ s[j] -= mean; vs = fmaf(s[j], s[j], vs); }
#pragma unroll
    for (int off = 1; off < 8; off <<= 1) vs += __shfl_xor(vs, off);
    float rstd = rsqrtf(vs*(1.f/192.f) + 1e-5f);
    unsigned short vb[24];
#pragma unroll
    for (int j = 0; j < 6; j++){
      float4 g4 = *(const float4*)(gamma + c0 + j*4);
      float4 b4 = *(const float4*)(beta  + c0 + j*4);
      float4 z4 = *(const float4*)(zs + (size_t)row*192 + c0 + j*4);
      vb[j*4+0] = f2b((s[j*4+0]*rstd*g4.x + b4.x)*z4.x);
      vb[j*4+1] = f2b((s[j*4+1]*rstd*g4.y + b4.y)*z4.y);
      vb[j*4+2] = f2b((s[j*4+2]*rstd*g4.z + b4.z)*z4.z);
      vb[j*4+3] = f2b((s[j*4+3]*rstd*g4.w + b4.w)*z4.w);
    }
#pragma unroll
    for (int j = 0; j < 3; j++)
      *(ushort8*)(Ash + row_l*200 + c0 + j*8) = *(ushort8*)(vb + j*8);
  }
  __syncthreads();
  const int lane = tid & 63, w = tid >> 6;
  const int wm = w & 1, wn = w >> 1;
  const int n = lane & 15, q = lane >> 4;
  const int m0 = blockIdx.x*32 + wm*16;
  f32x4 acc[3] = {};
#pragma unroll
  for (int k32 = 0; k32 < 6; k32++){
    int kb = k32*32 + q*8;
    short8 a = *(const short8*)(Ash + (wm*16 + n)*200 + kb);
#pragma unroll
    for (int j = 0; j < 3; j++){
      int nt = wn*3 + j;
      short8 bfr = *(const short8*)(Wfout + ((size_t)(k32*6 + nt)*64 + lane)*8);
      acc[j] = __builtin_amdgcn_mfma_f32_16x16x32_bf16(a, bfr, acc[j], 0, 0, 0);
    }
  }
#pragma unroll
  for (int j = 0; j < 3; j++){
    int nn = wn*48 + j*16 + n;
    float bv = bout[nn];
#pragma unroll
    for (int reg = 0; reg < 4; reg++){
      int m = m0 + q*4 + reg;
      out[(size_t)m*96 + nn] = acc[j][reg] + bv;
    }
  }
}

extern "C" void kernel_launch(void* const* d_in, const int* in_sizes, int n_in,
                              void* d_out, int out_size, void* d_ws, size_t ws_size,
                              hipStream_t stream)
{
  const float* x      = (const float*)d_in[0];
  const float* W_in   = (const float*)d_in[1];
  const float* b_in   = (const float*)d_in[2];
  const float* conv_w = (const float*)d_in[3];
  const float* conv_b = (const float*)d_in[4];
  const float* W_xp   = (const float*)d_in[5];
  const float* b_xp   = (const float*)d_in[6];
  const float* W_dt   = (const float*)d_in[7];
  const float* b_dt   = (const float*)d_in[8];
  const float* A_log  = (const float*)d_in[9];
  const float* D_skip = (const float*)d_in[10];
  const float* dt_bias= (const float*)d_in[11];
  const float* W_out  = (const float*)d_in[12];
  const float* b_out  = (const float*)d_in[13];
  const float* gamma  = (const float*)d_in[14];
  const float* beta   = (const float*)d_in[15];
  float* out = (float*)d_out;

  // Fully disjoint layout (floats). Total ~40.0M floats = 160 MB (< 256 MB ws).
  float* ws    = (float*)d_ws;
  float* xx    = ws;                 // 1572864
  float* zs    = ws + 1572864;       // 1572864
  float* xc    = ws + 3145728;       // 1572864
  float* xdbl  = ws + 4718592;       // 1572864
  float* ysb   = ws + 6291456;       // 6291456
  float* Sb    = ws + 12582912;      // 6291456 (NCK=256)
  float* H0    = ws + 18874368;      // 6291456
  float* sdtb  = ws + 25165824;      // 393216
  float* dts_c = ws + 25559040;      // 196608
  float* ylcs  = ws + 25755648;      // 12582912 (float2 stream {yloc,csdt})
  unsigned short* xcb   = (unsigned short*)(ws + 38338560); // 1572864 ushort
  unsigned short* xcTb  = xcb + 1572864;                    // 1572864 ushort
  unsigned short* Wf    = (unsigned short*)(ws + 39911424); // 147456 ushort
  unsigned short* Wfin  = (unsigned short*)(ws + 39985152); // 36864 ushort
  unsigned short* Wfout = (unsigned short*)(ws + 40003584); // 18432 ushort

  k_pack     <<<99,             256, 0, stream>>>(W_xp, W_in, W_out, Wf, Wfin, Wfout);
  k_gemm_in  <<<256,            256, 0, stream>>>(x, Wfin, b_in, xx, zs);
  k_conv     <<<6144,           256, 0, stream>>>(xx, conv_w, conv_b, xc, xcb, xcTb);
  k_gemm_xdbl<<<dim3(64, 2, 2), 256, 0, stream>>>(xcb, xcTb, Wf, b_xp, xdbl, dts_c);
  k_scanA    <<<1536,           256, 0, stream>>>(xc, xdbl, dts_c, A_log, W_dt, b_dt, dt_bias, D_skip, ylcs, sdtb, Sb);
  k_scanB    <<<384,            64,  0, stream>>>(A_log, sdtb, Sb, H0);
  k_scanC    <<<1536,           256, 0, stream>>>(xdbl, A_log, ylcs, H0, ysb);
  k_lngemm   <<<256,            256, 0, stream>>>(ysb, zs, gamma, beta, Wfout, b_out, out);
}